// Round 1
// baseline (154.833 us; speedup 1.0000x reference)
//
#include <hip/hip_runtime.h>
#include <cstdint>
#include <cstddef>

#define BATCH 8
#define NPTS  2048
#define CH1   64
#define CH2   128
#define NSAMP 64

// ---------------------------------------------------------------------------
// Kernel 1: per-point MLP  h2[b][m][p] = relu(W2 @ relu(W1 @ x[b][m] + b1) + b2)
// The MLP is independent of the gather index, so we evaluate it once per point
// (16384 evals) instead of once per (query, neighbor) pair (1M evals).
// Block = 128 threads (one per output channel p). W2 staged transposed in LDS.
// ---------------------------------------------------------------------------
__global__ __launch_bounds__(128) void mlp_kernel(
    const float* __restrict__ x,
    const float* __restrict__ W1, const float* __restrict__ b1,
    const float* __restrict__ W2, const float* __restrict__ b2,
    float* __restrict__ h2) {
  __shared__ float w2s[CH1][CH2];   // transposed: w2s[o][p]; bank = p%32 -> 2-way (free)
  __shared__ float h1s[CH1];

  const int tid = threadIdx.x;

  // Stage W2 (128x64 row-major) transposed into LDS. One-time cost per block.
  for (int i = tid; i < CH1 * CH2; i += 128) {
    int p = i >> 6;      // row of W2
    int o = i & 63;      // col of W2
    w2s[o][p] = W2[i];
  }
  const float bias2 = b2[tid];
  float w10 = 0.f, w11 = 0.f, w12 = 0.f, bias1 = 0.f;
  if (tid < CH1) {
    w10 = W1[tid * 3 + 0];
    w11 = W1[tid * 3 + 1];
    w12 = W1[tid * 3 + 2];
    bias1 = b1[tid];
  }
  __syncthreads();

  const int ptsPerBlock = (BATCH * NPTS) / gridDim.x;
  const int base = blockIdx.x * ptsPerBlock;

  for (int it = 0; it < ptsPerBlock; ++it) {
    const int pt = base + it;
    const float x0 = x[pt * 3 + 0];
    const float x1 = x[pt * 3 + 1];
    const float x2 = x[pt * 3 + 2];
    if (tid < CH1) {
      float h = fmaf(w12, x2, fmaf(w11, x1, fmaf(w10, x0, bias1)));
      h1s[tid] = fmaxf(h, 0.f);
    }
    __syncthreads();
    float acc = bias2;
#pragma unroll
    for (int o = 0; o < CH1; ++o) {
      acc = fmaf(w2s[o][tid], h1s[o], acc);
    }
    h2[(size_t)pt * CH2 + tid] = fmaxf(acc, 0.f);
    __syncthreads();   // protect h1s before next iteration overwrites it
  }
}

// ---------------------------------------------------------------------------
// Kernel 2: ball query + max-pool over the per-point feature table.
// One wave (64 lanes) per query point. Scan candidates in ascending index
// order in chunks of 64 (ballot), take the first 64 in-radius hits, and
// max-accumulate h2 rows (lane handles channels p=lane and p=lane+64).
// Distance in float64 to make the discrete inclusion decision robust.
// Early exit once 64 hits are found (~3 of 32 chunks on average).
// ---------------------------------------------------------------------------
__global__ __launch_bounds__(256) void query_kernel(
    const float* __restrict__ x,
    const float* __restrict__ h2,
    float* __restrict__ out) {
  const int wave = threadIdx.x >> 6;
  const int lane = threadIdx.x & 63;
  const int q = blockIdx.x * 4 + wave;   // global query id, 0 .. B*N-1
  const int b = q >> 11;                 // q / 2048
  const int s = q & (NPTS - 1);          // q % 2048

  const float* xb = x + (size_t)b * NPTS * 3;
  const float qx = xb[s * 3 + 0];
  const float qy = xb[s * 3 + 1];
  const float qz = xb[s * 3 + 2];
  const double dq = (double)qx * qx + (double)qy * qy + (double)qz * qz;

  const float* h2b = h2 + (size_t)b * NPTS * CH2;

  float acc0 = 0.f;   // relu output => h2 >= 0, and count >= 1 always (self)
  float acc1 = 0.f;
  int count = 0;

  for (int chunk = 0; chunk < NPTS; chunk += 64) {
    const int m = chunk + lane;
    const float px = xb[m * 3 + 0];
    const float py = xb[m * 3 + 1];
    const float pz = xb[m * 3 + 2];
    const double dm = (double)px * px + (double)py * py + (double)pz * pz;
    const double dot = (double)qx * px + (double)qy * py + (double)qz * pz;
    const double dist = dq + dm - 2.0 * dot;
    // reference: excluded iff dist > R*R  (R*R = 0.36 in double)
    unsigned long long mask = __ballot(!(dist > 0.36));

    while (mask) {
      const int bit = __builtin_ctzll(mask);
      mask &= mask - 1;
      const int mm = chunk + bit;                 // wave-uniform hit index
      acc0 = fmaxf(acc0, h2b[(size_t)mm * CH2 + lane]);
      acc1 = fmaxf(acc1, h2b[(size_t)mm * CH2 + 64 + lane]);
      if (++count == NSAMP) break;
    }
    if (count == NSAMP) break;
  }

  // out layout: (B, 128, 2048) -> out[b][p][s]
  const size_t ob = (size_t)b * CH2 * NPTS;
  out[ob + (size_t)lane * NPTS + s] = acc0;
  out[ob + (size_t)(lane + 64) * NPTS + s] = acc1;
}

// ---------------------------------------------------------------------------
extern "C" void kernel_launch(void* const* d_in, const int* in_sizes, int n_in,
                              void* d_out, int out_size, void* d_ws, size_t ws_size,
                              hipStream_t stream) {
  const float* x  = (const float*)d_in[0];   // (8, 2048, 3)
  const float* W1 = (const float*)d_in[1];   // (64, 3)
  const float* b1 = (const float*)d_in[2];   // (64,)
  const float* W2 = (const float*)d_in[3];   // (128, 64)
  const float* b2 = (const float*)d_in[4];   // (128,)
  float* out = (float*)d_out;                // (8, 128, 2048)

  float* h2 = (float*)d_ws;                  // 8*2048*128 floats = 8 MB scratch

  mlp_kernel<<<256, 128, 0, stream>>>(x, W1, b1, W2, b2, h2);
  query_kernel<<<(BATCH * NPTS) / 4, 256, 0, stream>>>(x, h2, out);
}

// Round 2
// 134.847 us; speedup vs baseline: 1.1482x; 1.1482x over previous
//
#include <hip/hip_runtime.h>
#include <hip/hip_fp16.h>
#include <cstdint>
#include <cstddef>

#define BATCH 8
#define NPTS  2048
#define CH1   64
#define CH2   128
#define NSAMP 64
#define MLP_PTS_PER_BLOCK 16

__device__ inline __half2 hmax2(__half2 a, __half2 b) {
  return __halves2half2(__hmax(__low2half(a), __low2half(b)),
                        __hmax(__high2half(a), __high2half(b)));
}

// ---------------------------------------------------------------------------
// Kernel 1: per-point MLP -> fp16 feature table h2[pt][128].
// 1024 blocks x 256 threads; each block stages W2^T once (32 KB LDS) and
// processes 16 points, 2 in flight (threads 0-127 -> point A, 128-255 -> B).
// ---------------------------------------------------------------------------
__global__ __launch_bounds__(256) void mlp_kernel(
    const float* __restrict__ x,
    const float* __restrict__ W1, const float* __restrict__ b1,
    const float* __restrict__ W2, const float* __restrict__ b2,
    __half* __restrict__ h2) {
  __shared__ float w2s[CH1][CH2];   // transposed: w2s[o][p]; lane->p consecutive => 2-way (free)
  __shared__ float h1s[2][CH1];

  const int t = threadIdx.x;
  const int half_id = t >> 7;       // which of the 2 in-flight points
  const int p = t & 127;            // output channel

  // Stage W2 (128x64 row-major) transposed into LDS.
  for (int i = t; i < CH1 * CH2; i += 256) {
    int wp = i >> 6;                // row (out channel) of W2
    int o  = i & 63;                // col (h1 channel)
    w2s[o][wp] = W2[i];
  }
  const float bias2 = b2[p];
  float w10 = 0.f, w11 = 0.f, w12 = 0.f, bias1 = 0.f;
  if (p < CH1) {
    w10 = W1[p * 3 + 0];
    w11 = W1[p * 3 + 1];
    w12 = W1[p * 3 + 2];
    bias1 = b1[p];
  }
  __syncthreads();

  const int base = blockIdx.x * MLP_PTS_PER_BLOCK;
  for (int it = 0; it < MLP_PTS_PER_BLOCK; it += 2) {
    const int pt = base + it + half_id;
    const float x0 = x[pt * 3 + 0];
    const float x1 = x[pt * 3 + 1];
    const float x2 = x[pt * 3 + 2];
    if (p < CH1) {
      float h = fmaf(w12, x2, fmaf(w11, x1, fmaf(w10, x0, bias1)));
      h1s[half_id][p] = fmaxf(h, 0.f);
    }
    __syncthreads();
    float acc = bias2;
#pragma unroll
    for (int o = 0; o < CH1; ++o) {
      acc = fmaf(w2s[o][p], h1s[half_id][o], acc);
    }
    h2[(size_t)pt * CH2 + p] = __float2half(fmaxf(acc, 0.f));
    __syncthreads();   // protect h1s before next pair overwrites it
  }
}

// ---------------------------------------------------------------------------
// Kernel 2: ball query + max-pool.
// One wave per query. Phase 1: ballot + prefix-rank builds hit list (<=64
// ascending indices) in LDS, no serial bit-extraction loop. Phase 2: hits
// processed 8 at a time with independent half2 loads (vmcnt pipelining),
// tree-max via v_pk_max_f16. Distance decision in fp64 (matched np exactly).
// ---------------------------------------------------------------------------
__global__ __launch_bounds__(256) void query_kernel(
    const float* __restrict__ x,
    const __half* __restrict__ h2,
    float* __restrict__ out) {
  __shared__ int list[4][NSAMP + 8];   // per-wave hit list, padded to mult of 8

  const int wave = threadIdx.x >> 6;
  const int lane = threadIdx.x & 63;
  const int q = blockIdx.x * 4 + wave;   // global query id
  const int b = q >> 11;
  const int s = q & (NPTS - 1);

  const float* xb = x + (size_t)b * NPTS * 3;
  const float qx = xb[s * 3 + 0];
  const float qy = xb[s * 3 + 1];
  const float qz = xb[s * 3 + 2];
  const double dq = (double)qx * qx + (double)qy * qy + (double)qz * qz;
  const unsigned long long lt = (1ull << lane) - 1ull;

  // ---- Phase 1: build ascending-order hit list (first NSAMP in-radius) ----
  int count = 0;
  for (int chunk = 0; chunk < NPTS && count < NSAMP; chunk += 64) {
    const int m = chunk + lane;
    const float px = xb[m * 3 + 0];
    const float py = xb[m * 3 + 1];
    const float pz = xb[m * 3 + 2];
    const double dm = (double)px * px + (double)py * py + (double)pz * pz;
    const double dot = (double)qx * px + (double)qy * py + (double)qz * pz;
    const bool hit = !((dq + dm - 2.0 * dot) > 0.36);
    const unsigned long long mask = __ballot(hit);
    if (hit) {
      const int pos = count + __popcll(mask & lt);
      if (pos < NSAMP) list[wave][pos] = m;
    }
    count += __popcll(mask);
  }
  if (count > NSAMP) count = NSAMP;
  // pad to multiple of 8 with a duplicate of the first hit (self is always a hit)
  const int padded = (count + 7) & ~7;
  if (lane < padded - count) list[wave][count + lane] = list[wave][0];

  // ---- Phase 2: max-pool fp16 feature rows, 8 hits per round ----
  const __half2* h2b = (const __half2*)(h2 + (size_t)b * NPTS * CH2);
  // lane handles channels {2*lane, 2*lane+1}: one half2 (dword) per hit
  __half2 acc = __float2half2_rn(0.f);   // relu output => h2 >= 0
  for (int i = 0; i < padded; i += 8) {
    const int m0 = list[wave][i + 0];
    const int m1 = list[wave][i + 1];
    const int m2 = list[wave][i + 2];
    const int m3 = list[wave][i + 3];
    const int m4 = list[wave][i + 4];
    const int m5 = list[wave][i + 5];
    const int m6 = list[wave][i + 6];
    const int m7 = list[wave][i + 7];
    const __half2 v0 = h2b[(size_t)m0 * 64 + lane];
    const __half2 v1 = h2b[(size_t)m1 * 64 + lane];
    const __half2 v2 = h2b[(size_t)m2 * 64 + lane];
    const __half2 v3 = h2b[(size_t)m3 * 64 + lane];
    const __half2 v4 = h2b[(size_t)m4 * 64 + lane];
    const __half2 v5 = h2b[(size_t)m5 * 64 + lane];
    const __half2 v6 = h2b[(size_t)m6 * 64 + lane];
    const __half2 v7 = h2b[(size_t)m7 * 64 + lane];
    __half2 t0 = hmax2(v0, v1);
    __half2 t1 = hmax2(v2, v3);
    __half2 t2 = hmax2(v4, v5);
    __half2 t3 = hmax2(v6, v7);
    t0 = hmax2(t0, t1);
    t2 = hmax2(t2, t3);
    acc = hmax2(acc, hmax2(t0, t2));
  }

  // out layout: (B, 128, 2048) -> out[b][p][s]; lane owns p = 2*lane, 2*lane+1
  const size_t ob = (size_t)b * CH2 * NPTS;
  out[ob + (size_t)(2 * lane)     * NPTS + s] = __low2float(acc);
  out[ob + (size_t)(2 * lane + 1) * NPTS + s] = __high2float(acc);
}

// ---------------------------------------------------------------------------
extern "C" void kernel_launch(void* const* d_in, const int* in_sizes, int n_in,
                              void* d_out, int out_size, void* d_ws, size_t ws_size,
                              hipStream_t stream) {
  const float* x  = (const float*)d_in[0];   // (8, 2048, 3)
  const float* W1 = (const float*)d_in[1];   // (64, 3)
  const float* b1 = (const float*)d_in[2];   // (64,)
  const float* W2 = (const float*)d_in[3];   // (128, 64)
  const float* b2 = (const float*)d_in[4];   // (128,)
  float* out = (float*)d_out;                // (8, 128, 2048)

  __half* h2 = (__half*)d_ws;                // 16384 * 128 fp16 = 4 MB scratch

  mlp_kernel<<<(BATCH * NPTS) / MLP_PTS_PER_BLOCK, 256, 0, stream>>>(
      x, W1, b1, W2, b2, h2);
  query_kernel<<<(BATCH * NPTS) / 4, 256, 0, stream>>>(x, h2, out);
}

// Round 3
// 119.066 us; speedup vs baseline: 1.3004x; 1.1325x over previous
//
#include <hip/hip_runtime.h>
#include <hip/hip_fp16.h>
#include <cstdint>
#include <cstddef>

#define BATCH 8
#define NPTS  2048
#define CH1   64
#define CH2   128
#define NSAMP 64
#define MLP_PTS 32              // points per mlp block

__device__ inline __half2 hmax2(__half2 a, __half2 b) {
  return __halves2half2(__hmax(__low2half(a), __low2half(b)),
                        __hmax(__high2half(a), __high2half(b)));
}

// ---------------------------------------------------------------------------
// Kernel 1: per-point MLP -> fp16 feature table h2[pt][128], plus sqm[pt].
// W2 row kept in 64 VGPRs per thread (loaded once per block; L1/L2-hot).
// 8 points in flight; h1 read back as wave-uniform float4 broadcasts
// (ds_read_b128, conflict-free). No transposed LDS staging (the R2 version
// had a 64-way bank conflict on w2s[o][p] stores).
// ---------------------------------------------------------------------------
__global__ __launch_bounds__(256) void mlp_kernel(
    const float* __restrict__ x,
    const float* __restrict__ W1, const float* __restrict__ b1,
    const float* __restrict__ W2, const float* __restrict__ b2,
    __half* __restrict__ h2, float* __restrict__ sqm) {
  __shared__ float h1s[CH1][8];      // [channel][point-in-octet]

  const int t = threadIdx.x;
  const int p = t & 127;             // output channel
  const int g = t >> 7;              // 0/1 -> which 4 points of the octet
  const int base = blockIdx.x * MLP_PTS;

  // --- squared norms for the query kernel (one thread per point) ---
  if (t < MLP_PTS) {
    const int pt = base + t;
    const float X = x[pt * 3 + 0];
    const float Y = x[pt * 3 + 1];
    const float Z = x[pt * 3 + 2];
    sqm[pt] = fmaf(Z, Z, fmaf(Y, Y, X * X));
  }

  // --- W2 row p into registers (once per block) ---
  float w2r[CH1];
  {
    const float4* w2row = (const float4*)(W2 + (size_t)p * CH1);
#pragma unroll
    for (int i = 0; i < CH1 / 4; ++i) {
      const float4 v = w2row[i];
      w2r[4 * i + 0] = v.x;
      w2r[4 * i + 1] = v.y;
      w2r[4 * i + 2] = v.z;
      w2r[4 * i + 3] = v.w;
    }
  }
  const float bias2 = b2[p];

  // layer-1 weights for this thread's (o1) channel
  const int o1 = t & 63;
  const float w10 = W1[o1 * 3 + 0];
  const float w11 = W1[o1 * 3 + 1];
  const float w12 = W1[o1 * 3 + 2];
  const float bi1 = b1[o1];
  const int j0 = t >> 6;             // 0..3 -> handles octet slots j0, j0+4

  for (int oct = 0; oct < MLP_PTS; oct += 8) {
    // ---- layer 1: h1s[o][j] for 8 points ----
#pragma unroll
    for (int r = 0; r < 2; ++r) {
      const int jj = j0 + 4 * r;
      const int pt = base + oct + jj;
      const float X = x[pt * 3 + 0];
      const float Y = x[pt * 3 + 1];
      const float Z = x[pt * 3 + 2];
      const float h = fmaf(w12, Z, fmaf(w11, Y, fmaf(w10, X, bi1)));
      h1s[o1][jj] = fmaxf(h, 0.f);
    }
    __syncthreads();

    // ---- layer 2: channel p for 4 points (group g) ----
    float acc0 = bias2, acc1 = bias2, acc2 = bias2, acc3 = bias2;
    const float4* h1v = (const float4*)&h1s[0][0];   // [o][4g..4g+3] = h1v[2o+g]
#pragma unroll
    for (int o = 0; o < CH1; ++o) {
      const float4 h = h1v[2 * o + g];               // wave-uniform broadcast
      acc0 = fmaf(w2r[o], h.x, acc0);
      acc1 = fmaf(w2r[o], h.y, acc1);
      acc2 = fmaf(w2r[o], h.z, acc2);
      acc3 = fmaf(w2r[o], h.w, acc3);
    }
    const int pt0 = base + oct + 4 * g;
    h2[(size_t)(pt0 + 0) * CH2 + p] = __float2half(fmaxf(acc0, 0.f));
    h2[(size_t)(pt0 + 1) * CH2 + p] = __float2half(fmaxf(acc1, 0.f));
    h2[(size_t)(pt0 + 2) * CH2 + p] = __float2half(fmaxf(acc2, 0.f));
    h2[(size_t)(pt0 + 3) * CH2 + p] = __float2half(fmaxf(acc3, 0.f));
    __syncthreads();   // protect h1s before next octet overwrites it
  }
}

// ---------------------------------------------------------------------------
// Kernel 2: ball query + max-pool. One wave per query.
// Phase 1: fp32 distance with a +-3e-5 guard band around 0.36; fp64
// recompute only when a lane lands in the band (~0.5% of chunks), so the
// discrete decision is bit-identical to the fp64 np reference.
// Phase 2: hit list from LDS, 8 independent half2 loads per round.
// ---------------------------------------------------------------------------
__global__ __launch_bounds__(256) void query_kernel(
    const float* __restrict__ x,
    const float* __restrict__ sqm,
    const __half* __restrict__ h2,
    float* __restrict__ out) {
  __shared__ int list[4][NSAMP + 8];

  const int wave = threadIdx.x >> 6;
  const int lane = threadIdx.x & 63;
  const int q = blockIdx.x * 4 + wave;
  const int b = q >> 11;
  const int s = q & (NPTS - 1);

  const float* xb = x + (size_t)b * NPTS * 3;
  const float* sqb = sqm + (size_t)b * NPTS;
  const float qx = xb[s * 3 + 0];
  const float qy = xb[s * 3 + 1];
  const float qz = xb[s * 3 + 2];
  const float dqf = sqb[s];
  const double dq = (double)qx * qx + (double)qy * qy + (double)qz * qz;
  const unsigned long long lt = (1ull << lane) - 1ull;

  // ---- Phase 1: first NSAMP in-radius hits, ascending index ----
  int count = 0;
  for (int chunk = 0; chunk < NPTS && count < NSAMP; chunk += 64) {
    const int m = chunk + lane;
    const float px = xb[m * 3 + 0];
    const float py = xb[m * 3 + 1];
    const float pz = xb[m * 3 + 2];
    const float sq = sqb[m];
    const float dot = fmaf(qz, pz, fmaf(qy, py, qx * px));
    const float dist = fmaf(-2.f, dot, dqf + sq);
    bool hit;
    if (__ballot(__builtin_fabsf(dist - 0.36f) <= 3e-5f)) {
      // rare exact path: fp64 for the whole chunk
      const double dm = (double)px * px + (double)py * py + (double)pz * pz;
      const double dd = (double)qx * px + (double)qy * py + (double)qz * pz;
      hit = !((dq + dm - 2.0 * dd) > 0.36);
    } else {
      hit = !(dist > 0.36f);
    }
    const unsigned long long mask = __ballot(hit);
    if (hit) {
      const int pos = count + __popcll(mask & lt);
      if (pos < NSAMP) list[wave][pos] = m;
    }
    count += __popcll(mask);
  }
  if (count > NSAMP) count = NSAMP;
  const int padded = (count + 7) & ~7;   // pad with first hit (self is a hit)
  if (lane < padded - count) list[wave][count + lane] = list[wave][0];

  // ---- Phase 2: max-pool fp16 feature rows, 8 hits per round ----
  const __half2* h2b = (const __half2*)(h2 + (size_t)b * NPTS * CH2);
  __half2 acc = __float2half2_rn(0.f);
  for (int i = 0; i < padded; i += 8) {
    const int m0 = list[wave][i + 0];
    const int m1 = list[wave][i + 1];
    const int m2 = list[wave][i + 2];
    const int m3 = list[wave][i + 3];
    const int m4 = list[wave][i + 4];
    const int m5 = list[wave][i + 5];
    const int m6 = list[wave][i + 6];
    const int m7 = list[wave][i + 7];
    const __half2 v0 = h2b[(size_t)m0 * 64 + lane];
    const __half2 v1 = h2b[(size_t)m1 * 64 + lane];
    const __half2 v2 = h2b[(size_t)m2 * 64 + lane];
    const __half2 v3 = h2b[(size_t)m3 * 64 + lane];
    const __half2 v4 = h2b[(size_t)m4 * 64 + lane];
    const __half2 v5 = h2b[(size_t)m5 * 64 + lane];
    const __half2 v6 = h2b[(size_t)m6 * 64 + lane];
    const __half2 v7 = h2b[(size_t)m7 * 64 + lane];
    __half2 t0 = hmax2(v0, v1);
    __half2 t1 = hmax2(v2, v3);
    __half2 t2 = hmax2(v4, v5);
    __half2 t3 = hmax2(v6, v7);
    t0 = hmax2(t0, t1);
    t2 = hmax2(t2, t3);
    acc = hmax2(acc, hmax2(t0, t2));
  }

  // out: (B, 128, 2048); lane owns channels 2*lane, 2*lane+1
  const size_t ob = (size_t)b * CH2 * NPTS;
  out[ob + (size_t)(2 * lane)     * NPTS + s] = __low2float(acc);
  out[ob + (size_t)(2 * lane + 1) * NPTS + s] = __high2float(acc);
}

// ---------------------------------------------------------------------------
extern "C" void kernel_launch(void* const* d_in, const int* in_sizes, int n_in,
                              void* d_out, int out_size, void* d_ws, size_t ws_size,
                              hipStream_t stream) {
  const float* x  = (const float*)d_in[0];
  const float* W1 = (const float*)d_in[1];
  const float* b1 = (const float*)d_in[2];
  const float* W2 = (const float*)d_in[3];
  const float* b2 = (const float*)d_in[4];
  float* out = (float*)d_out;

  __half* h2  = (__half*)d_ws;                                   // 4 MB
  float*  sqm = (float*)((char*)d_ws + (size_t)4 * 1024 * 1024); // 64 KB

  mlp_kernel<<<(BATCH * NPTS) / MLP_PTS, 256, 0, stream>>>(
      x, W1, b1, W2, b2, h2, sqm);
  query_kernel<<<(BATCH * NPTS) / 4, 256, 0, stream>>>(x, sqm, h2, out);
}

// Round 4
// 107.065 us; speedup vs baseline: 1.4462x; 1.1121x over previous
//
#include <hip/hip_runtime.h>
#include <hip/hip_fp16.h>
#include <cstdint>
#include <cstddef>

#define BATCH 8
#define NPTS  2048
#define CH1   64
#define CH2   128
#define NSAMP 64

typedef _Float16 half8v  __attribute__((ext_vector_type(8)));
typedef float    float4v __attribute__((ext_vector_type(4)));
typedef unsigned uint4v  __attribute__((ext_vector_type(4)));

__device__ inline unsigned pkmax(unsigned a, unsigned b) {
  unsigned d;
  asm("v_pk_max_f16 %0, %1, %2" : "=v"(d) : "v"(a), "v"(b));
  return d;
}

// ---------------------------------------------------------------------------
// Kernel 1: per-point MLP via MFMA.  h2(p, pt) = relu(W2 @ relu(W1 x + b1) + b2)
// is a 128 x 16384 x 64 GEMM. One wave per 16-point tile; 256 blocks x 4 waves.
// - A fragments: W2 in fp16, 8 m-tiles x 2 k-frags, held in VGPRs (loaded once).
//   A[m = lane&15][k = quad*8 + j]  (m89/attention-note layout).
// - B fragments: h1 computed in-register (3 FMA + relu per value) and packed.
//   B[k = quad*8 + j][n = lane&15].
// - C/D: col = lane&15 (point), row = quad*4 + reg (channel). Bias preloaded.
// Also emits xyzq[pt] = {x, y, z, |p|^2} for the query kernel's phase 1.
// ---------------------------------------------------------------------------
__global__ __launch_bounds__(256) void mlp_kernel(
    const float* __restrict__ x,
    const float* __restrict__ W1, const float* __restrict__ b1,
    const float* __restrict__ W2, const float* __restrict__ b2,
    __half* __restrict__ h2, float4v* __restrict__ xyzq) {
  const int t = threadIdx.x;
  const int wave = t >> 6;
  const int lane = t & 63;
  const int n = lane & 15;          // point within tile (B/D column)
  const int quad = lane >> 4;       // 0..3
  const int base = blockIdx.x * 64; // 64 points per block (4 tiles)

  // packed coord+norm table for the query kernel
  if (t < 64) {
    const int pt = base + t;
    const float X = x[pt * 3 + 0];
    const float Y = x[pt * 3 + 1];
    const float Z = x[pt * 3 + 2];
    float4v v;
    v[0] = X; v[1] = Y; v[2] = Z; v[3] = fmaf(Z, Z, fmaf(Y, Y, X * X));
    xyzq[pt] = v;
  }

  // W1 rows for this lane's 16 h1 channels: o = quad*8+j (j<8) and o+32
  float w1x[16], w1y[16], w1z[16], b1v[16];
#pragma unroll
  for (int j = 0; j < 16; ++j) {
    const int o = quad * 8 + (j & 7) + ((j < 8) ? 0 : 32);
    w1x[j] = W1[o * 3 + 0];
    w1y[j] = W1[o * 3 + 1];
    w1z[j] = W1[o * 3 + 2];
    b1v[j] = b1[o];
  }

  // W2 A-fragments (fp16), loaded once: afrag[mtile][kfrag]
  half8v afrag[8][2];
#pragma unroll
  for (int mt = 0; mt < 8; ++mt) {
    const int m = mt * 16 + n;
#pragma unroll
    for (int kf = 0; kf < 2; ++kf) {
      const float4v* wp = (const float4v*)(W2 + m * CH1 + kf * 32 + quad * 8);
      const float4v lo = wp[0];
      const float4v hi = wp[1];
#pragma unroll
      for (int e = 0; e < 4; ++e) {
        afrag[mt][kf][e]     = (_Float16)lo[e];
        afrag[mt][kf][4 + e] = (_Float16)hi[e];
      }
    }
  }

  // bias fragments: reg r of mtile mt holds channel mt*16 + quad*4 + r
  float4v bias[8];
#pragma unroll
  for (int mt = 0; mt < 8; ++mt)
    bias[mt] = *(const float4v*)(b2 + mt * 16 + quad * 4);

  // ---- this wave's tile: layer 1 in registers ----
  const int pt = base + wave * 16 + n;
  const float X = x[pt * 3 + 0];
  const float Y = x[pt * 3 + 1];
  const float Z = x[pt * 3 + 2];
  half8v bf0, bf1;
#pragma unroll
  for (int j = 0; j < 8; ++j) {
    const float ha = fmaxf(fmaf(w1z[j], Z, fmaf(w1y[j], Y, fmaf(w1x[j], X, b1v[j]))), 0.f);
    const float hb = fmaxf(fmaf(w1z[8 + j], Z, fmaf(w1y[8 + j], Y, fmaf(w1x[8 + j], X, b1v[8 + j]))), 0.f);
    bf0[j] = (_Float16)ha;
    bf1[j] = (_Float16)hb;
  }

  // ---- layer 2: 16 MFMA, epilogue relu + fp16 store ----
  __half* hrow = h2 + (size_t)pt * CH2;
#pragma unroll
  for (int mt = 0; mt < 8; ++mt) {
    float4v acc = bias[mt];
    acc = __builtin_amdgcn_mfma_f32_16x16x32_f16(afrag[mt][0], bf0, acc, 0, 0, 0);
    acc = __builtin_amdgcn_mfma_f32_16x16x32_f16(afrag[mt][1], bf1, acc, 0, 0, 0);
    const int p0 = mt * 16 + quad * 4;
    const __half2 lo2 = __halves2half2(__float2half(fmaxf(acc[0], 0.f)),
                                       __float2half(fmaxf(acc[1], 0.f)));
    const __half2 hi2 = __halves2half2(__float2half(fmaxf(acc[2], 0.f)),
                                       __float2half(fmaxf(acc[3], 0.f)));
    *(__half2*)(hrow + p0)     = lo2;
    *(__half2*)(hrow + p0 + 2) = hi2;
  }
}

// ---------------------------------------------------------------------------
// Kernel 2: ball query + max-pool. One wave per query.
// Phase 1: one float4 load per candidate (xyzq), fp32 distance with fp64
// guard band (decisions bit-exact vs np). Hit list in LDS, padded to 64.
// Phase 2: lane = (hit-slot h = lane&7, channel-slice c = lane>>3); per round
// lane loads 16 fp16 channels of one hit (2 dwordx4), 8 rounds fixed.
// Cross-lane xor-butterfly (ds_swizzle over h bits) for the final max.
// ---------------------------------------------------------------------------
__global__ __launch_bounds__(256) void query_kernel(
    const float4v* __restrict__ xyzq,
    const __half* __restrict__ h2,
    float* __restrict__ out) {
  __shared__ int list[4][NSAMP];

  const int wave = threadIdx.x >> 6;
  const int lane = threadIdx.x & 63;
  const int q = blockIdx.x * 4 + wave;
  const int b = q >> 11;
  const int s = q & (NPTS - 1);

  const float4v* xq = xyzq + (size_t)b * NPTS;
  const float4v qv = xq[s];
  const float qx = qv[0], qy = qv[1], qz = qv[2], dqf = qv[3];
  const double dq = (double)qx * qx + (double)qy * qy + (double)qz * qz;
  const unsigned long long lt = (1ull << lane) - 1ull;

  // ---- Phase 1: first NSAMP in-radius hits, ascending index ----
  int count = 0;
  for (int chunk = 0; chunk < NPTS && count < NSAMP; chunk += 64) {
    const int m = chunk + lane;
    const float4v pv = xq[m];
    const float px = pv[0], py = pv[1], pz = pv[2];
    const float dot = fmaf(qz, pz, fmaf(qy, py, qx * px));
    const float dist = fmaf(-2.f, dot, dqf + pv[3]);
    bool hit;
    if (__ballot(__builtin_fabsf(dist - 0.36f) <= 3e-5f)) {
      // rare exact path: fp64, same evaluation order as the np reference
      const double dm = (double)px * px + (double)py * py + (double)pz * pz;
      const double dd = (double)qx * px + (double)qy * py + (double)qz * pz;
      hit = !((dq + dm - 2.0 * dd) > 0.36);
    } else {
      hit = !(dist > 0.36f);
    }
    const unsigned long long mask = __ballot(hit);
    if (hit) {
      const int pos = count + __popcll(mask & lt);
      if (pos < NSAMP) list[wave][pos] = m;
    }
    count += __popcll(mask);
  }
  if (count > NSAMP) count = NSAMP;
  const int first = list[wave][0];      // self is always a hit -> valid
  if (lane >= count) list[wave][lane] = first;

  // ---- Phase 2: 8 hits/round x 16 channels/lane ----
  const int h = lane & 7;    // hit slot
  const int c = lane >> 3;   // channel slice (16 ch)
  const char* hb = (const char*)h2 + (size_t)b * NPTS * CH2 * 2 + c * 32;
  unsigned a0 = 0, a1 = 0, a2 = 0, a3 = 0, a4 = 0, a5 = 0, a6 = 0, a7 = 0;
#pragma unroll
  for (int r = 0; r < 8; ++r) {
    const int m = list[wave][r * 8 + h];
    const char* p = hb + m * 256;
    const uint4v va = *(const uint4v*)p;
    const uint4v vb = *(const uint4v*)(p + 16);
    a0 = pkmax(a0, va[0]); a1 = pkmax(a1, va[1]);
    a2 = pkmax(a2, va[2]); a3 = pkmax(a3, va[3]);
    a4 = pkmax(a4, vb[0]); a5 = pkmax(a5, vb[1]);
    a6 = pkmax(a6, vb[2]); a7 = pkmax(a7, vb[3]);
  }

  // xor-butterfly over hit-slot bits (lane bits 0..2), within 32-lane rows
#define RED_STEP(IMM)                                                        \
  a0 = pkmax(a0, (unsigned)__builtin_amdgcn_ds_swizzle((int)a0, IMM));       \
  a1 = pkmax(a1, (unsigned)__builtin_amdgcn_ds_swizzle((int)a1, IMM));       \
  a2 = pkmax(a2, (unsigned)__builtin_amdgcn_ds_swizzle((int)a2, IMM));       \
  a3 = pkmax(a3, (unsigned)__builtin_amdgcn_ds_swizzle((int)a3, IMM));       \
  a4 = pkmax(a4, (unsigned)__builtin_amdgcn_ds_swizzle((int)a4, IMM));       \
  a5 = pkmax(a5, (unsigned)__builtin_amdgcn_ds_swizzle((int)a5, IMM));       \
  a6 = pkmax(a6, (unsigned)__builtin_amdgcn_ds_swizzle((int)a6, IMM));       \
  a7 = pkmax(a7, (unsigned)__builtin_amdgcn_ds_swizzle((int)a7, IMM));
  RED_STEP(0x041F)   // xor 1
  RED_STEP(0x081F)   // xor 2
  RED_STEP(0x101F)   // xor 4
#undef RED_STEP

  // every lane now holds the full 16-ch max for slice c; lane writes half2 #h
  const unsigned s1 = (h & 1) ? a1 : a0;
  const unsigned s2 = (h & 1) ? a3 : a2;
  const unsigned s3 = (h & 1) ? a5 : a4;
  const unsigned s4 = (h & 1) ? a7 : a6;
  const unsigned t1 = (h & 2) ? s2 : s1;
  const unsigned t2 = (h & 2) ? s4 : s3;
  const unsigned vsel = (h & 4) ? t2 : t1;
  const __half2 hv = *(const __half2*)&vsel;

  const int p0 = c * 16 + 2 * h;
  const size_t ob = (size_t)b * CH2 * NPTS;
  out[ob + (size_t)p0 * NPTS + s]       = __low2float(hv);
  out[ob + (size_t)(p0 + 1) * NPTS + s] = __high2float(hv);
}

// ---------------------------------------------------------------------------
extern "C" void kernel_launch(void* const* d_in, const int* in_sizes, int n_in,
                              void* d_out, int out_size, void* d_ws, size_t ws_size,
                              hipStream_t stream) {
  const float* x  = (const float*)d_in[0];
  const float* W1 = (const float*)d_in[1];
  const float* b1 = (const float*)d_in[2];
  const float* W2 = (const float*)d_in[3];
  const float* b2 = (const float*)d_in[4];
  float* out = (float*)d_out;

  __half*  h2   = (__half*)d_ws;                                   // 4 MB
  float4v* xyzq = (float4v*)((char*)d_ws + (size_t)4 * 1024 * 1024); // 256 KB

  mlp_kernel<<<(BATCH * NPTS) / 64, 256, 0, stream>>>(
      x, W1, b1, W2, b2, h2, xyzq);
  query_kernel<<<(BATCH * NPTS) / 4, 256, 0, stream>>>(xyzq, h2, out);
}